// Round 12
// baseline (102.322 us; speedup 1.0000x reference)
//
#include <hip/hip_runtime.h>
#include <hip/hip_bf16.h>
#include <math.h>

#define Nn    64
#define RPB   4
#define NRAYS 16384
#define NEARV 2.0f
#define FARV  6.0f

typedef __attribute__((ext_vector_type(8))) short bf16x8;
typedef __attribute__((ext_vector_type(4))) float f32x4;
typedef __attribute__((ext_vector_type(2))) float f32x2;

// ---- DPP wave64 primitives ----
template <int CTRL, int RMASK>
__device__ __forceinline__ float dpp_mv(float x, float ident) {
  return __int_as_float(__builtin_amdgcn_update_dpp(
      __float_as_int(ident), __float_as_int(x), CTRL, RMASK, 0xf, false));
}
// row_shr stage with bound_ctrl=1: invalid source lanes read 0 -> fusable v_add_f32_dpp
template <int CTRL>
__device__ __forceinline__ float dpp_shr0(float x) {
  return __int_as_float(__builtin_amdgcn_update_dpp(
      0, __float_as_int(x), CTRL, 0xf, 0xf, true));
}
__device__ __forceinline__ float shfl_up1(float x) {   // lane i <- i-1, lane0 keeps
  return __int_as_float(__builtin_amdgcn_update_dpp(
      __float_as_int(x), __float_as_int(x), 0x138, 0xf, 0xf, false));
}
__device__ __forceinline__ float shfl_dn1(float x) {   // lane i <- i+1, lane63 keeps
  return __int_as_float(__builtin_amdgcn_update_dpp(
      __float_as_int(x), __float_as_int(x), 0x130, 0xf, 0xf, false));
}
__device__ __forceinline__ float scan_add_dpp(float x) {
  x += dpp_shr0<0x111>(x);
  x += dpp_shr0<0x112>(x);
  x += dpp_shr0<0x114>(x);
  x += dpp_shr0<0x118>(x);
  x += dpp_mv<0x142, 0xa>(x, 0.f);   // row_bcast:15 -> rows 1,3
  x += dpp_mv<0x143, 0xc>(x, 0.f);   // row_bcast:31 -> rows 2,3
  return x;
}
__device__ __forceinline__ float scan_mul_dpp(float x) {
  x *= dpp_mv<0x111, 0xf>(x, 1.f);
  x *= dpp_mv<0x112, 0xf>(x, 1.f);
  x *= dpp_mv<0x114, 0xf>(x, 1.f);
  x *= dpp_mv<0x118, 0xf>(x, 1.f);
  x *= dpp_mv<0x142, 0xa>(x, 1.f);
  x *= dpp_mv<0x143, 0xc>(x, 1.f);
  return x;
}
__device__ __forceinline__ float reduce_add_bcast(float x) {
  x = scan_add_dpp(x);
  return __int_as_float(__builtin_amdgcn_readlane(__float_as_int(x), 63));
}

__device__ __forceinline__ float fast_rcp(float x) { return __builtin_amdgcn_rcpf(x); }
__device__ __forceinline__ float sigmoidf_fast(float x) { return fast_rcp(1.f + __expf(-x)); }

__device__ __forceinline__ short bfhi_bits(float x) { return (short)(__float_as_uint(x) >> 16); }
__device__ __forceinline__ float bfhi_val(float x)  { return __uint_as_float(__float_as_uint(x) & 0xFFFF0000u); }

// ---- bitonic sort of 64 unique keys across the wave (ascending by lane) ----
template <int LEVEL, int D>
__device__ __forceinline__ void bitonic_stage(unsigned& k, int lane) {
  unsigned t;
  if constexpr (D == 32) {
    t = (unsigned)__builtin_amdgcn_ds_bpermute((lane ^ 32) << 2, (int)k);
  } else {
    t = (unsigned)__builtin_amdgcn_ds_swizzle((int)k, (D << 10) | 0x1F);
  }
  const bool bitd = (lane & D) != 0;
  const bool desc = (lane & (1 << LEVEL)) != 0;
  const unsigned mn = (k < t) ? k : t;
  const unsigned mx = (k < t) ? t : k;
  k = (bitd == desc) ? mn : mx;
}
template <int LEVEL, int D>
struct BSort {
  static __device__ __forceinline__ void run(unsigned& k, int lane) {
    bitonic_stage<LEVEL, D>(k, lane);
    if constexpr (D > 1) BSort<LEVEL, D / 2>::run(k, lane);
    else if constexpr (LEVEL < 6) BSort<LEVEL + 1, (1 << LEVEL)>::run(k, lane);
  }
};

// ---- one ascending bitonic-merge stage on a 64-lane bitonic array ----
template <int D>
__device__ __forceinline__ void merge_stage(unsigned& k, int lane) {
  unsigned t;
  if constexpr (D == 32) {
    t = (unsigned)__builtin_amdgcn_ds_bpermute((lane ^ 32) << 2, (int)k);
  } else {
    t = (unsigned)__builtin_amdgcn_ds_swizzle((int)k, (D << 10) | 0x1F);
  }
  const unsigned mn = (k < t) ? k : t;
  const unsigned mx = (k < t) ? t : k;
  k = ((lane & D) != 0) ? mx : mn;
}
__device__ __forceinline__ void merge64(unsigned& k, int lane) {
  merge_stage<32>(k, lane);
  merge_stage<16>(k, lane);
  merge_stage<8>(k, lane);
  merge_stage<4>(k, lane);
  merge_stage<2>(k, lane);
  merge_stage<1>(k, lane);
}

// searchsorted(cdf[0..62], u, 'right'); first step (idx=63) can never take -> start at 32
__device__ __forceinline__ int count_le_f(float arr, float x) {
  int cnt = 0;
#pragma unroll
  for (int step = 32; step >= 1; step >>= 1) {
    const int idx = cnt + step - 1;
    const float v = __shfl(arr, idx, 64);
    if (idx < 63 && v <= x) cnt += step;
  }
  return cnt;
}

// Field eval, 64 samples/ray: D = W2^T(4x64) @ h^T(64x64) via 16x16x32 bf16 MFMA.
// SPLITB (coarse): trunc split both operands, Ahi*Bhi+Ahi*Blo+Alo*Bhi (exact R4 numerics).
// !SPLITB (fine): B single RNE, Ahi*B + Alo*B (fine feeds only the final composite).
template <bool SPLITB>
__device__ __forceinline__ void field_eval(
    float zlane, const f32x2 c0v[2][4], const f32x2 c1v[2][4],
    const bf16x8 aHi[2], const bf16x8 aLo[2],
    float b20, float b21, float b22, float b23,
    int quad, int col, float4* scratch, float o[4]) {
#pragma unroll
  for (int nt = 0; nt < 4; ++nt) {
    f32x4 acc = {0.f, 0.f, 0.f, 0.f};
    const float zm = __shfl(zlane, nt * 16 + col, 64);
    const f32x2 zm2 = {zm, zm};
#pragma unroll
    for (int ks = 0; ks < 2; ++ks) {
      union { bf16x8 v; unsigned u[4]; } Bhi, Blo;
#pragma unroll
      for (int p = 0; p < 4; ++p) {
        f32x2 h = zm2 * c1v[ks][p] + c0v[ks][p];             // v_pk_fma_f32
        h = __builtin_elementwise_max(h, (f32x2){0.f, 0.f}); // v_pk_max_f32
        if constexpr (SPLITB) {
          union { f32x2 f; unsigned u[2]; } U; U.f = h;
          Bhi.u[p] = __builtin_amdgcn_perm(U.u[1], U.u[0], 0x07060302u);
          union { unsigned u[2]; f32x2 f; } M;
          M.u[0] = U.u[0] & 0xFFFF0000u;
          M.u[1] = U.u[1] & 0xFFFF0000u;
          const f32x2 l = h - M.f;
          union { f32x2 f; unsigned u[2]; } L; L.f = l;
          Blo.u[p] = __builtin_amdgcn_perm(L.u[1], L.u[0], 0x07060302u);
        } else {
          __hip_bfloat162 t = __float22bfloat162_rn(make_float2(h[0], h[1]));
          Bhi.u[p] = *reinterpret_cast<unsigned*>(&t);
        }
      }
      if constexpr (SPLITB) {
        acc = __builtin_amdgcn_mfma_f32_16x16x32_bf16(aHi[ks], Bhi.v, acc, 0, 0, 0);
        acc = __builtin_amdgcn_mfma_f32_16x16x32_bf16(aHi[ks], Blo.v, acc, 0, 0, 0);
        acc = __builtin_amdgcn_mfma_f32_16x16x32_bf16(aLo[ks], Bhi.v, acc, 0, 0, 0);
      } else {
        acc = __builtin_amdgcn_mfma_f32_16x16x32_bf16(aHi[ks], Bhi.v, acc, 0, 0, 0);
        acc = __builtin_amdgcn_mfma_f32_16x16x32_bf16(aLo[ks], Bhi.v, acc, 0, 0, 0);
      }
    }
    if (quad == 0) scratch[nt * 16 + col] = make_float4(acc[0], acc[1], acc[2], acc[3]);
  }
  const float4 r = scratch[(threadIdx.x & 63)];  // same-wave LDS ordering
  o[0] = r.x + b20; o[1] = r.y + b21; o[2] = r.z + b22; o[3] = r.w + b23;
}

__global__ __launch_bounds__(RPB * 64, 4) void nerf_fused(
    const float* __restrict__ ray_o, const float* __restrict__ ray_d,
    const float* __restrict__ tform, const float* __restrict__ noise,
    const float* __restrict__ usmp,  const float* __restrict__ W1,
    const float* __restrict__ b1,    const float* __restrict__ W2,
    const float* __restrict__ b2,    float* __restrict__ out) {
  const int wave = threadIdx.x >> 6;
  const int lane = threadIdx.x & 63;
  const int ray  = blockIdx.x * RPB + wave;
  const int quad = lane >> 4;
  const int col  = lane & 15;

  // All LDS wave-private: no __syncthreads anywhere.
  __shared__ float2 sC [RPB][Nn];
  __shared__ float4 sPk[RPB][2 * Nn];   // payload by ORIGINAL index; [64..127] doubles as eval scratch

  const float o0 = ray_o[ray * 3 + 0], o1 = ray_o[ray * 3 + 1], o2 = ray_o[ray * 3 + 2];
  float d0 = ray_d[ray * 3 + 0], d1 = ray_d[ray * 3 + 1], d2 = ray_d[ray * 3 + 2];
  const float rn = __builtin_amdgcn_rsqf(d0 * d0 + d1 * d1 + d2 * d2);
  d0 *= rn; d1 *= rn; d2 *= rn;

  {
    const float w10 = W1[lane], w11 = W1[64 + lane], w12 = W1[128 + lane];
    const float c1 = d0 * w10 + d1 * w11 + d2 * w12;
    const float c0 = o0 * w10 + o1 * w11 + o2 * w12 + b1[lane];
    sC[wave][lane] = make_float2(c0, c1);
  }

  // coarse z (strictly increasing in lane); z in [2, 6.07) -> bits monotone
  const float nz = noise[ray * Nn + lane];
  const float z  = NEARV + (FARV - NEARV) * ((float)lane + nz) * (1.0f / Nn);
  const unsigned kc = ((__float_as_uint(z) - 0x40000000u) << 7) | (unsigned)lane;

  f32x2 c0v[2][4], c1v[2][4];
#pragma unroll
  for (int ks = 0; ks < 2; ++ks) {
    const float4* cc4 = (const float4*)&sC[wave][0];
    const int base4 = (ks * 32 + quad * 8) >> 1;
#pragma unroll
    for (int jj = 0; jj < 4; ++jj) {
      const float4 v = cc4[base4 + jj];
      c0v[ks][jj] = (f32x2){v.x, v.z};
      c1v[ks][jj] = (f32x2){v.y, v.w};
    }
  }

  bf16x8 aHi[2], aLo[2];
#pragma unroll
  for (int ks = 0; ks < 2; ++ks) {
#pragma unroll
    for (int j = 0; j < 8; ++j) {
      const int k = ks * 32 + quad * 8 + j;
      const float wv  = (col < 4) ? W2[k * 4 + col] : 0.f;
      aHi[ks][j] = bfhi_bits(wv);
      aLo[ks][j] = bfhi_bits(wv - bfhi_val(wv));
    }
  }
  const float b20 = b2[0], b21 = b2[1], b22 = b2[2], b23 = b2[3];
  float4* scratch = &sPk[wave][64];

  // ---- coarse field eval (exact split numerics) ----
  float oc[4];
  field_eval<true>(z, c0v, c1v, aHi, aLo, b20, b21, b22, b23, quad, col, scratch, oc);
  const float sig = oc[0];
  const float cr = sigmoidf_fast(oc[1]), cg = sigmoidf_fast(oc[2]), cb = sigmoidf_fast(oc[3]);
  sPk[wave][lane] = make_float4(sig, cr, cg, cb);   // coarse payload, orig idx = lane

  // ---- coarse compositing weights + smoothed pdf/cdf ----
  const float zn   = shfl_dn1(z);
  const float dist = (lane == 63) ? 1e10f : (zn - z);
  const float alpha = 1.f - __expf(-fmaxf(sig, 0.f) * dist);
  float cdfreg, binreg;
  {
    const float P  = scan_mul_dpp(1.f - alpha + 1e-10f);
    float Te = shfl_up1(P);
    if (lane == 0) Te = 1.f;
    const float w = alpha * Te;

    const float mxA = fmaxf(shfl_up1(w), w);
    const float mxB = fmaxf(w, shfl_dn1(w));
    const float sm = 0.5f * (mxA + mxB) + 0.01f;

    const float v   = ((unsigned)(lane - 1) <= 61u) ? sm : 0.f;
    const float tot = reduce_add_bcast(v);
    const float pdf = v * fast_rcp(tot);
    const float C   = scan_add_dpp(pdf);
    cdfreg = (lane == 0) ? 0.f : C;
    binreg = 0.5f * (z + zn);
  }

  // ---- inverse-CDF sampling ----
  const float u = usmp[ray * Nn + lane];
  const int lo_i = count_le_f(cdfreg, u);
  const int below = lo_i - 1;
  const int above = (lo_i < 63) ? lo_i : 62;
  const float cdfb = __shfl(cdfreg, below, 64);
  const float cdfa = __shfl(cdfreg, above, 64);
  const float binb = __shfl(binreg, below, 64);
  const float bina = __shfl(binreg, above, 64);
  float den = cdfa - cdfb;
  if (den < 1e-5f) den = 1.f;
  const float zs = fmaf((u - cdfb) * fast_rcp(den), bina - binb, binb);

  // ---- key sort (depends only on zs) ----
  const unsigned kf = ((__float_as_uint(zs) - 0x40000000u) << 7) | (unsigned)(64 + lane);
  unsigned kfS = kf;
  BSort<1, 1>::run(kfS, lane);                      // fine sorted ascending by lane

  // ---- fine field eval (A-split only, B single RNE) ----
  float of[4];
  field_eval<false>(zs, c0v, c1v, aHi, aLo, b20, b21, b22, b23, quad, col, scratch, of);

  // bitonic 128-seq: lo = coarse asc, hi = fine reversed (desc)
  unsigned lok = kc;
  unsigned hik = (unsigned)__builtin_amdgcn_ds_bpermute((63 - lane) << 2, (int)kfS);
  {
    const unsigned mn = (lok < hik) ? lok : hik;
    const unsigned mx = (lok < hik) ? hik : lok;
    lok = mn; hik = mx;                             // half-cleaner: lo[i]<=hi[j] for all
  }
  merge64(lok, lane);                               // sorted[0..63]  by lane
  merge64(hik, lane);                               // sorted[64..127] by lane

  const float sigF = of[0];
  const float fr = sigmoidf_fast(of[1]), fg = sigmoidf_fast(of[2]), fb = sigmoidf_fast(of[3]);
  sPk[wave][64 + lane] = make_float4(sigF, fr, fg, fb);  // fine payload, orig idx = 64+lane

  // rearrange: lane i needs sorted[2i], sorted[2i+1]
  const int a0 = ((2 * lane) & 63) << 2;
  const int a1 = ((2 * lane + 1) & 63) << 2;
  const unsigned l0 = (unsigned)__builtin_amdgcn_ds_bpermute(a0, (int)lok);
  const unsigned h0 = (unsigned)__builtin_amdgcn_ds_bpermute(a0, (int)hik);
  const unsigned l1 = (unsigned)__builtin_amdgcn_ds_bpermute(a1, (int)lok);
  const unsigned h1 = (unsigned)__builtin_amdgcn_ds_bpermute(a1, (int)hik);
  const unsigned k0 = (lane < 32) ? l0 : h0;
  const unsigned k1 = (lane < 32) ? l1 : h1;

  // decode z (bit-exact) and gather payload by original index
  const float z0 = __uint_as_float((k0 >> 7) + 0x40000000u);
  const float z1 = __uint_as_float((k1 >> 7) + 0x40000000u);
  const float4 q0 = sPk[wave][k0 & 127u];
  const float4 q1 = sPk[wave][k1 & 127u];

  // ---- final compositing over 128 sorted samples (2 per lane) ----
  const float z2 = shfl_dn1(z0);
  const float dist0 = z1 - z0;
  const float dist1 = (lane == 63) ? 1e10f : (z2 - z1);
  const float al0 = 1.f - __expf(-fmaxf(q0.x, 0.f) * dist0);
  const float al1 = 1.f - __expf(-fmaxf(q1.x, 0.f) * dist1);
  const float aa0 = 1.f - al0 + 1e-10f;
  const float aa1 = 1.f - al1 + 1e-10f;
  const float Pp = scan_mul_dpp(aa0 * aa1);
  float Tp = shfl_up1(Pp);
  if (lane == 0) Tp = 1.f;
  const float w0 = al0 * Tp;
  const float w1 = al1 * Tp * aa0;

  const float accR = reduce_add_bcast(w0 * q0.y + w1 * q1.y);
  const float accG = reduce_add_bcast(w0 * q0.z + w1 * q1.z);
  const float accB = reduce_add_bcast(w0 * q0.w + w1 * q1.w);
  const float accD = reduce_add_bcast(w0 * z0 + w1 * z1);
  const float accM = reduce_add_bcast(w0 + w1);

  if (lane == 0) {
    const float* tf = tform + (ray >> 12) * 16;
    const float vz = d0 * tf[2] + d1 * tf[6] + d2 * tf[10];
    out[ray * 3 + 0]     = accR;
    out[ray * 3 + 1]     = accG;
    out[ray * 3 + 2]     = accB;
    out[NRAYS * 3 + ray] = -vz * accD;
    out[NRAYS * 4 + ray] = accM;
  }
}

extern "C" void kernel_launch(void* const* d_in, const int* in_sizes, int n_in,
                              void* d_out, int out_size, void* d_ws, size_t ws_size,
                              hipStream_t stream) {
  const float* ray_o = (const float*)d_in[0];
  const float* ray_d = (const float*)d_in[1];
  const float* tform = (const float*)d_in[2];
  const float* noise = (const float*)d_in[3];
  const float* usmp  = (const float*)d_in[4];
  const float* W1    = (const float*)d_in[5];
  const float* b1    = (const float*)d_in[6];
  const float* W2    = (const float*)d_in[7];
  const float* b2    = (const float*)d_in[8];
  float* out = (float*)d_out;

  nerf_fused<<<dim3(NRAYS / RPB), RPB * 64, 0, stream>>>(
      ray_o, ray_d, tform, noise, usmp, W1, b1, W2, b2, out);
}

// Round 13
// 100.966 us; speedup vs baseline: 1.0134x; 1.0134x over previous
//
#include <hip/hip_runtime.h>
#include <hip/hip_bf16.h>
#include <math.h>

#define Nn    64
#define RPB   2
#define NRAYS 16384
#define NEARV 2.0f
#define FARV  6.0f

typedef __attribute__((ext_vector_type(8))) short bf16x8;
typedef __attribute__((ext_vector_type(4))) float f32x4;
typedef __attribute__((ext_vector_type(2))) float f32x2;

// ---- DPP wave64 primitives ----
template <int CTRL, int RMASK>
__device__ __forceinline__ float dpp_mv(float x, float ident) {
  return __int_as_float(__builtin_amdgcn_update_dpp(
      __float_as_int(ident), __float_as_int(x), CTRL, RMASK, 0xf, false));
}
__device__ __forceinline__ float shfl_up1(float x) {   // lane i <- i-1, lane0 keeps
  return __int_as_float(__builtin_amdgcn_update_dpp(
      __float_as_int(x), __float_as_int(x), 0x138, 0xf, 0xf, false));
}
__device__ __forceinline__ float shfl_dn1(float x) {   // lane i <- i+1, lane63 keeps
  return __int_as_float(__builtin_amdgcn_update_dpp(
      __float_as_int(x), __float_as_int(x), 0x130, 0xf, 0xf, false));
}
__device__ __forceinline__ float scan_add_dpp(float x) {
  x += dpp_mv<0x111, 0xf>(x, 0.f);
  x += dpp_mv<0x112, 0xf>(x, 0.f);
  x += dpp_mv<0x114, 0xf>(x, 0.f);
  x += dpp_mv<0x118, 0xf>(x, 0.f);
  x += dpp_mv<0x142, 0xa>(x, 0.f);   // row_bcast:15 -> rows 1,3
  x += dpp_mv<0x143, 0xc>(x, 0.f);   // row_bcast:31 -> rows 2,3
  return x;
}
__device__ __forceinline__ float scan_mul_dpp(float x) {
  x *= dpp_mv<0x111, 0xf>(x, 1.f);
  x *= dpp_mv<0x112, 0xf>(x, 1.f);
  x *= dpp_mv<0x114, 0xf>(x, 1.f);
  x *= dpp_mv<0x118, 0xf>(x, 1.f);
  x *= dpp_mv<0x142, 0xa>(x, 1.f);
  x *= dpp_mv<0x143, 0xc>(x, 1.f);
  return x;
}
__device__ __forceinline__ float reduce_add_bcast(float x) {
  x = scan_add_dpp(x);
  return __int_as_float(__builtin_amdgcn_readlane(__float_as_int(x), 63));
}

__device__ __forceinline__ float fast_rcp(float x) { return __builtin_amdgcn_rcpf(x); }
__device__ __forceinline__ float sigmoidf_fast(float x) { return fast_rcp(1.f + __expf(-x)); }

__device__ __forceinline__ short bfhi_bits(float x) { return (short)(__float_as_uint(x) >> 16); }
__device__ __forceinline__ float bfhi_val(float x)  { return __uint_as_float(__float_as_uint(x) & 0xFFFF0000u); }

// ---- bitonic sort of 64 unique keys across the wave (ascending by lane) ----
template <int LEVEL, int D>
__device__ __forceinline__ void bitonic_stage(unsigned& k, int lane) {
  unsigned t;
  if constexpr (D == 32) {
    t = (unsigned)__builtin_amdgcn_ds_bpermute((lane ^ 32) << 2, (int)k);
  } else {
    t = (unsigned)__builtin_amdgcn_ds_swizzle((int)k, (D << 10) | 0x1F);
  }
  const bool bitd = (lane & D) != 0;
  const bool desc = (lane & (1 << LEVEL)) != 0;
  const unsigned mn = (k < t) ? k : t;
  const unsigned mx = (k < t) ? t : k;
  k = (bitd == desc) ? mn : mx;
}
template <int LEVEL, int D>
struct BSort {
  static __device__ __forceinline__ void run(unsigned& k, int lane) {
    bitonic_stage<LEVEL, D>(k, lane);
    if constexpr (D > 1) BSort<LEVEL, D / 2>::run(k, lane);
    else if constexpr (LEVEL < 6) BSort<LEVEL + 1, (1 << LEVEL)>::run(k, lane);
  }
};

// ---- one ascending bitonic-merge stage on a 64-lane bitonic array ----
template <int D>
__device__ __forceinline__ void merge_stage(unsigned& k, int lane) {
  unsigned t;
  if constexpr (D == 32) {
    t = (unsigned)__builtin_amdgcn_ds_bpermute((lane ^ 32) << 2, (int)k);
  } else {
    t = (unsigned)__builtin_amdgcn_ds_swizzle((int)k, (D << 10) | 0x1F);
  }
  const unsigned mn = (k < t) ? k : t;
  const unsigned mx = (k < t) ? t : k;
  k = ((lane & D) != 0) ? mx : mn;
}
__device__ __forceinline__ void merge64(unsigned& k, int lane) {
  merge_stage<32>(k, lane);
  merge_stage<16>(k, lane);
  merge_stage<8>(k, lane);
  merge_stage<4>(k, lane);
  merge_stage<2>(k, lane);
  merge_stage<1>(k, lane);
}

// searchsorted(cdf[0..62], u, 'right'); first step (idx=63) can never take -> start at 32
__device__ __forceinline__ int count_le_f(float arr, float x) {
  int cnt = 0;
#pragma unroll
  for (int step = 32; step >= 1; step >>= 1) {
    const int idx = cnt + step - 1;
    const float v = __shfl(arr, idx, 64);
    if (idx < 63 && v <= x) cnt += step;
  }
  return cnt;
}

// Field eval, 64 samples/ray: D = W2^T(4x64) @ h^T(64x64) via 16x16x32 bf16 MFMA.
// SPLITB (coarse): trunc split both operands, Ahi*Bhi+Ahi*Blo+Alo*Bhi (exact R4 numerics).
// !SPLITB (fine): B single RNE, Ahi*B + Alo*B (fine feeds only the final composite).
template <bool SPLITB>
__device__ __forceinline__ void field_eval(
    float zlane, const f32x2 c0v[2][4], const f32x2 c1v[2][4],
    const bf16x8 aHi[2], const bf16x8 aLo[2],
    float b20, float b21, float b22, float b23,
    int quad, int col, float4* scratch, float o[4]) {
#pragma unroll
  for (int nt = 0; nt < 4; ++nt) {
    f32x4 acc = {0.f, 0.f, 0.f, 0.f};
    const float zm = __shfl(zlane, nt * 16 + col, 64);
    const f32x2 zm2 = {zm, zm};
#pragma unroll
    for (int ks = 0; ks < 2; ++ks) {
      union { bf16x8 v; unsigned u[4]; } Bhi, Blo;
#pragma unroll
      for (int p = 0; p < 4; ++p) {
        f32x2 h = zm2 * c1v[ks][p] + c0v[ks][p];             // v_pk_fma_f32
        h = __builtin_elementwise_max(h, (f32x2){0.f, 0.f}); // v_pk_max_f32
        if constexpr (SPLITB) {
          union { f32x2 f; unsigned u[2]; } U; U.f = h;
          Bhi.u[p] = __builtin_amdgcn_perm(U.u[1], U.u[0], 0x07060302u);
          union { unsigned u[2]; f32x2 f; } M;
          M.u[0] = U.u[0] & 0xFFFF0000u;
          M.u[1] = U.u[1] & 0xFFFF0000u;
          const f32x2 l = h - M.f;
          union { f32x2 f; unsigned u[2]; } L; L.f = l;
          Blo.u[p] = __builtin_amdgcn_perm(L.u[1], L.u[0], 0x07060302u);
        } else {
          __hip_bfloat162 t = __float22bfloat162_rn(make_float2(h[0], h[1]));
          Bhi.u[p] = *reinterpret_cast<unsigned*>(&t);
        }
      }
      if constexpr (SPLITB) {
        acc = __builtin_amdgcn_mfma_f32_16x16x32_bf16(aHi[ks], Bhi.v, acc, 0, 0, 0);
        acc = __builtin_amdgcn_mfma_f32_16x16x32_bf16(aHi[ks], Blo.v, acc, 0, 0, 0);
        acc = __builtin_amdgcn_mfma_f32_16x16x32_bf16(aLo[ks], Bhi.v, acc, 0, 0, 0);
      } else {
        acc = __builtin_amdgcn_mfma_f32_16x16x32_bf16(aHi[ks], Bhi.v, acc, 0, 0, 0);
        acc = __builtin_amdgcn_mfma_f32_16x16x32_bf16(aLo[ks], Bhi.v, acc, 0, 0, 0);
      }
    }
    if (quad == 0) scratch[nt * 16 + col] = make_float4(acc[0], acc[1], acc[2], acc[3]);
  }
  const float4 r = scratch[(threadIdx.x & 63)];  // same-wave LDS ordering
  o[0] = r.x + b20; o[1] = r.y + b21; o[2] = r.z + b22; o[3] = r.w + b23;
}

__global__ __launch_bounds__(RPB * 64, 4) void nerf_fused(
    const float* __restrict__ ray_o, const float* __restrict__ ray_d,
    const float* __restrict__ tform, const float* __restrict__ noise,
    const float* __restrict__ usmp,  const float* __restrict__ W1,
    const float* __restrict__ b1,    const float* __restrict__ W2,
    const float* __restrict__ b2,    float* __restrict__ out) {
  const int wave = threadIdx.x >> 6;
  const int lane = threadIdx.x & 63;
  const int ray  = blockIdx.x * RPB + wave;
  const int quad = lane >> 4;
  const int col  = lane & 15;

  // All LDS wave-private: no __syncthreads anywhere.
  __shared__ float2 sC [RPB][Nn];
  __shared__ float4 sPk[RPB][2 * Nn];   // payload by ORIGINAL index; [64..127] doubles as eval scratch

  const float o0 = ray_o[ray * 3 + 0], o1 = ray_o[ray * 3 + 1], o2 = ray_o[ray * 3 + 2];
  float d0 = ray_d[ray * 3 + 0], d1 = ray_d[ray * 3 + 1], d2 = ray_d[ray * 3 + 2];
  const float rn = __builtin_amdgcn_rsqf(d0 * d0 + d1 * d1 + d2 * d2);
  d0 *= rn; d1 *= rn; d2 *= rn;

  {
    const float w10 = W1[lane], w11 = W1[64 + lane], w12 = W1[128 + lane];
    const float c1 = d0 * w10 + d1 * w11 + d2 * w12;
    const float c0 = o0 * w10 + o1 * w11 + o2 * w12 + b1[lane];
    sC[wave][lane] = make_float2(c0, c1);
  }

  // coarse z (strictly increasing in lane); z in [2, 6.07) -> bits monotone
  const float nz = noise[ray * Nn + lane];
  const float z  = NEARV + (FARV - NEARV) * ((float)lane + nz) * (1.0f / Nn);
  const unsigned kc = ((__float_as_uint(z) - 0x40000000u) << 7) | (unsigned)lane;

  f32x2 c0v[2][4], c1v[2][4];
#pragma unroll
  for (int ks = 0; ks < 2; ++ks) {
    const float4* cc4 = (const float4*)&sC[wave][0];
    const int base4 = (ks * 32 + quad * 8) >> 1;
#pragma unroll
    for (int jj = 0; jj < 4; ++jj) {
      const float4 v = cc4[base4 + jj];
      c0v[ks][jj] = (f32x2){v.x, v.z};
      c1v[ks][jj] = (f32x2){v.y, v.w};
    }
  }

  bf16x8 aHi[2], aLo[2];
#pragma unroll
  for (int ks = 0; ks < 2; ++ks) {
#pragma unroll
    for (int j = 0; j < 8; ++j) {
      const int k = ks * 32 + quad * 8 + j;
      const float wv  = (col < 4) ? W2[k * 4 + col] : 0.f;
      aHi[ks][j] = bfhi_bits(wv);
      aLo[ks][j] = bfhi_bits(wv - bfhi_val(wv));
    }
  }
  const float b20 = b2[0], b21 = b2[1], b22 = b2[2], b23 = b2[3];
  float4* scratch = &sPk[wave][64];

  // ---- coarse field eval (exact split numerics) ----
  float oc[4];
  field_eval<true>(z, c0v, c1v, aHi, aLo, b20, b21, b22, b23, quad, col, scratch, oc);
  const float sig = oc[0];
  const float cr = sigmoidf_fast(oc[1]), cg = sigmoidf_fast(oc[2]), cb = sigmoidf_fast(oc[3]);
  sPk[wave][lane] = make_float4(sig, cr, cg, cb);   // coarse payload, orig idx = lane

  // ---- coarse compositing weights + smoothed pdf/cdf ----
  const float zn   = shfl_dn1(z);
  const float dist = (lane == 63) ? 1e10f : (zn - z);
  const float alpha = 1.f - __expf(-fmaxf(sig, 0.f) * dist);
  float cdfreg, binreg;
  {
    const float P  = scan_mul_dpp(1.f - alpha + 1e-10f);
    float Te = shfl_up1(P);
    if (lane == 0) Te = 1.f;
    const float w = alpha * Te;

    const float mxA = fmaxf(shfl_up1(w), w);
    const float mxB = fmaxf(w, shfl_dn1(w));
    const float sm = 0.5f * (mxA + mxB) + 0.01f;

    const float v   = (lane >= 1 && lane <= 62) ? sm : 0.f;
    const float tot = reduce_add_bcast(v);
    const float pdf = v * fast_rcp(tot);
    const float C   = scan_add_dpp(pdf);
    cdfreg = (lane == 0) ? 0.f : C;
    binreg = 0.5f * (z + zn);
  }

  // ---- inverse-CDF sampling ----
  const float u = usmp[ray * Nn + lane];
  const int lo_i = count_le_f(cdfreg, u);
  const int below = lo_i - 1;
  const int above = (lo_i < 63) ? lo_i : 62;
  const float cdfb = __shfl(cdfreg, below, 64);
  const float cdfa = __shfl(cdfreg, above, 64);
  const float binb = __shfl(binreg, below, 64);
  const float bina = __shfl(binreg, above, 64);
  float den = cdfa - cdfb;
  if (den < 1e-5f) den = 1.f;
  const float zs = fmaf((u - cdfb) * fast_rcp(den), bina - binb, binb);

  // ---- key sort (depends only on zs) ----
  const unsigned kf = ((__float_as_uint(zs) - 0x40000000u) << 7) | (unsigned)(64 + lane);
  unsigned kfS = kf;
  BSort<1, 1>::run(kfS, lane);                      // fine sorted ascending by lane

  // ---- fine field eval (A-split only, B single RNE) ----
  float of[4];
  field_eval<false>(zs, c0v, c1v, aHi, aLo, b20, b21, b22, b23, quad, col, scratch, of);

  // bitonic 128-seq: lo = coarse asc, hi = fine reversed (desc)
  unsigned lok = kc;
  unsigned hik = (unsigned)__builtin_amdgcn_ds_bpermute((63 - lane) << 2, (int)kfS);
  {
    const unsigned mn = (lok < hik) ? lok : hik;
    const unsigned mx = (lok < hik) ? hik : lok;
    lok = mn; hik = mx;                             // half-cleaner: lo[i]<=hi[j] for all
  }
  merge64(lok, lane);                               // sorted[0..63]  by lane
  merge64(hik, lane);                               // sorted[64..127] by lane

  const float sigF = of[0];
  const float fr = sigmoidf_fast(of[1]), fg = sigmoidf_fast(of[2]), fb = sigmoidf_fast(of[3]);
  sPk[wave][64 + lane] = make_float4(sigF, fr, fg, fb);  // fine payload, orig idx = 64+lane

  // rearrange: lane i needs sorted[2i], sorted[2i+1]
  const int a0 = ((2 * lane) & 63) << 2;
  const int a1 = ((2 * lane + 1) & 63) << 2;
  const unsigned l0 = (unsigned)__builtin_amdgcn_ds_bpermute(a0, (int)lok);
  const unsigned h0 = (unsigned)__builtin_amdgcn_ds_bpermute(a0, (int)hik);
  const unsigned l1 = (unsigned)__builtin_amdgcn_ds_bpermute(a1, (int)lok);
  const unsigned h1 = (unsigned)__builtin_amdgcn_ds_bpermute(a1, (int)hik);
  const unsigned k0 = (lane < 32) ? l0 : h0;
  const unsigned k1 = (lane < 32) ? l1 : h1;

  // decode z (bit-exact) and gather payload by original index
  const float z0 = __uint_as_float((k0 >> 7) + 0x40000000u);
  const float z1 = __uint_as_float((k1 >> 7) + 0x40000000u);
  const float4 q0 = sPk[wave][k0 & 127u];
  const float4 q1 = sPk[wave][k1 & 127u];

  // ---- final compositing over 128 sorted samples (2 per lane) ----
  const float z2 = shfl_dn1(z0);
  const float dist0 = z1 - z0;
  const float dist1 = (lane == 63) ? 1e10f : (z2 - z1);
  const float al0 = 1.f - __expf(-fmaxf(q0.x, 0.f) * dist0);
  const float al1 = 1.f - __expf(-fmaxf(q1.x, 0.f) * dist1);
  const float aa0 = 1.f - al0 + 1e-10f;
  const float aa1 = 1.f - al1 + 1e-10f;
  const float Pp = scan_mul_dpp(aa0 * aa1);
  float Tp = shfl_up1(Pp);
  if (lane == 0) Tp = 1.f;
  const float w0 = al0 * Tp;
  const float w1 = al1 * Tp * aa0;

  const float accR = reduce_add_bcast(w0 * q0.y + w1 * q1.y);
  const float accG = reduce_add_bcast(w0 * q0.z + w1 * q1.z);
  const float accB = reduce_add_bcast(w0 * q0.w + w1 * q1.w);
  const float accD = reduce_add_bcast(w0 * z0 + w1 * z1);
  const float accM = reduce_add_bcast(w0 + w1);

  if (lane == 0) {
    const float* tf = tform + (ray >> 12) * 16;
    const float vz = d0 * tf[2] + d1 * tf[6] + d2 * tf[10];
    out[ray * 3 + 0]     = accR;
    out[ray * 3 + 1]     = accG;
    out[ray * 3 + 2]     = accB;
    out[NRAYS * 3 + ray] = -vz * accD;
    out[NRAYS * 4 + ray] = accM;
  }
}

extern "C" void kernel_launch(void* const* d_in, const int* in_sizes, int n_in,
                              void* d_out, int out_size, void* d_ws, size_t ws_size,
                              hipStream_t stream) {
  const float* ray_o = (const float*)d_in[0];
  const float* ray_d = (const float*)d_in[1];
  const float* tform = (const float*)d_in[2];
  const float* noise = (const float*)d_in[3];
  const float* usmp  = (const float*)d_in[4];
  const float* W1    = (const float*)d_in[5];
  const float* b1    = (const float*)d_in[6];
  const float* W2    = (const float*)d_in[7];
  const float* b2    = (const float*)d_in[8];
  float* out = (float*)d_out;

  nerf_fused<<<dim3(NRAYS / RPB), RPB * 64, 0, stream>>>(
      ray_o, ray_d, tform, noise, usmp, W1, b1, W2, b2, out);
}